// Round 18
// baseline (170.733 us; speedup 1.0000x reference)
//
#include <hip/hip_runtime.h>
#include <hip/hip_bf16.h>
#include <math.h>

#define N_PTS 8192
#define QPW 8                 // queries per wave (top-K roles)
#define QPW_REV 8             // queries per wave (reverse chamfer role)
#define WPB 4                 // waves per block
#define QPB (QPW * WPB)       // 32 queries per block (top-K roles)
#define BLKS_TOPK (N_PTS / QPB)        // 256 blocks per top-K role
#define BLKS_REV  (N_PTS / (QPW_REV * WPB))  // 256 blocks for rev

#define R0_END BLKS_TOPK                  // 256   curv2 scan
#define R1_END (2 * BLKS_TOPK)            // 512   pc1 scan
#define R3_END (3 * BLKS_TOPK)            // 768   cross scan
#define GRID_TOTAL (3 * BLKS_TOPK + BLKS_REV)  // 1024

// F_CHAMFER*ALPHA0 = 0.02, F_CURVATURE*ALPHA0 = 0.006, F_SMOOTH*ALPHA0 = 0.01
#define W_CHAM 0.02f
#define W_CURV 0.006f
#define W_SMOO 0.01f

#define BIGF 1e30f
#define IDX_MASK 0x1FFFu
#define KEY_MASK 0xFFFFE000u

__device__ __forceinline__ float mkkey(float d, unsigned idx) {
    return __uint_as_float((__float_as_uint(d) & KEY_MASK) | idx);
}
__device__ __forceinline__ int keyidx(float k) {
    return (int)(__float_as_uint(k) & IDX_MASK);
}
__device__ __forceinline__ unsigned monou(float k) {
    int b = __float_as_int(k);
    return (unsigned)(b ^ ((b >> 31) | 0x80000000));
}
__device__ __forceinline__ int prefcnt(unsigned long long m) {
    return __builtin_amdgcn_mbcnt_hi((unsigned)(m >> 32),
           __builtin_amdgcn_mbcnt_lo((unsigned)m, 0));
}

// ---- value-only sorted insert (fallback path only; proven) ----
template <int K>
__device__ __forceinline__ void kinsert(float kv, float (&bd)[K]) {
    bd[K - 1] = kv;
#pragma unroll
    for (int s = K - 1; s > 0; --s) {
        float lo = fminf(bd[s - 1], bd[s]);
        float hi = fmaxf(bd[s - 1], bd[s]);
        bd[s - 1] = lo; bd[s] = hi;
    }
}

// ---- proven sorted merge (cold failsafe only) ----
template <int K>
__device__ void merge_keys(float m1, float m2, float m3, float (&bd)[K], int lane) {
    float h0 = m1, h1 = m2, h2 = m3;
#pragma unroll
    for (int r = 0; r < K; ++r) {
        float bv = h0;
#pragma unroll
        for (int off = 1; off < 64; off <<= 1) bv = fminf(bv, __shfl_xor(bv, off));
        bd[r] = bv;
        if (h0 == bv) { h0 = h1; h1 = h2; h2 = BIGF; }
    }
}

// ---- exact fixed-tau FULL rescan in key space (proven) ----
template <int K>
__device__ void tau_rescan(const float4* __restrict__ cand,
                           float nqx, float nqy, float nqz, float tau,
                           float (&bd)[K], int lane) {
#pragma unroll
    for (int r = 0; r < K; ++r) bd[r] = BIGF;
    const float4* cp = cand + lane;
    unsigned ib = (unsigned)lane;
    for (int it = 0; it < N_PTS / 64; ++it) {
        float4 p = cp[it * 64];
        float d = fmaf(p.x, nqx, fmaf(p.y, nqy, fmaf(p.z, nqz, p.w)));
        float kc = mkkey(d, ib);
        unsigned long long m = __ballot(kc <= tau);
        while (m) {
            int b = __builtin_ctzll(m);
            m &= m - 1;
            float kv = __shfl(kc, b);
            if (kv < bd[K - 1]) kinsert<K>(kv, bd);
        }
        ib += 64;
    }
}

// ---- rank-pivot set selection (proven R17) ----
template <int K>
__device__ void select_set(const float4* __restrict__ cand,
                           float nqx, float nqy, float nqz,
                           float& k1, float& k2, float& k3,
                           bool& q1, bool& q2, bool& q3, float& km, int lane) {
    const unsigned u1 = monou(k1), u2 = monou(k2), u3 = monou(k3);
    unsigned lo = 0u, hi = 0xFFFFFFFFu, piv = 0u;
    int cnt = -1;
    unsigned long long b3 = 0ull;
    for (int it = 0; it < 34; ++it) {
        piv = lo + ((hi - lo) >> 1);
        unsigned long long b1 = __ballot(u1 <= piv);
        unsigned long long b2 = __ballot(u2 <= piv);
        b3 = __ballot(u3 <= piv);
        cnt = __popcll(b1) + __popcll(b2) + __popcll(b3);
        if (cnt == K) break;
        if (cnt < K) lo = piv + 1; else hi = piv - 1;
    }
    bool setok = (cnt == K);
    bool fail;
    float bdK[K];
    if (setok) {
        q1 = (u1 <= piv); q2 = (u2 <= piv); q3 = (u3 <= piv);
        float t = q3 ? k3 : (q2 ? k2 : (q1 ? k1 : -BIGF));
#pragma unroll
        for (int off = 1; off < 64; off <<= 1) t = fmaxf(t, __shfl_xor(t, off));
        km = t;
        fail = (b3 != 0ull);
    } else {
        merge_keys<K>(k1, k2, k3, bdK, lane);
        km = bdK[K - 1];
        fail = (__ballot(k3 <= km) != 0ull);
    }
    if (fail) { tau_rescan<K>(cand, nqx, nqy, nqz, km, bdK, lane); setok = false; }
    if (!setok) {
        float kv = BIGF;
#pragma unroll
        for (int r = 0; r < K; ++r) if (lane == r) kv = bdK[r];
        k1 = kv; k2 = BIGF; k3 = BIGF;
        q1 = (lane < K); q2 = false; q3 = false;
        km = bdK[K - 1];
    }
}

__device__ __forceinline__ void wave_add3(float& a, float& b, float& c) {
#pragma unroll
    for (int off = 1; off < 64; off <<= 1) {
        a += __shfl_xor(a, off);
        b += __shfl_xor(b, off);
        c += __shfl_xor(c, off);
    }
}
__device__ __forceinline__ void wave_add4(float& a, float& b, float& c, float& d) {
#pragma unroll
    for (int off = 1; off < 64; off <<= 1) {
        a += __shfl_xor(a, off);
        b += __shfl_xor(b, off);
        c += __shfl_xor(c, off);
        d += __shfl_xor(d, off);
    }
}

// ---- branchless Q-query key scan, 2-candidate strips (VGPR-lean for Q=8) ----
template <int Q>
__device__ __forceinline__ void scank(const float4* __restrict__ cand,
                                      const float (&nqx)[Q], const float (&nqy)[Q],
                                      const float (&nqz)[Q],
                                      float (&m1)[Q], float (&m2)[Q], float (&m3)[Q],
                                      int lane) {
#pragma unroll
    for (int qi = 0; qi < Q; ++qi) { m1[qi] = BIGF; m2[qi] = BIGF; m3[qi] = BIGF; }
    const float4* cp = cand + lane;
    unsigned ib = (unsigned)lane;
#pragma unroll 2
    for (int it = 0; it < N_PTS / 128; ++it) {
        float4 p0 = cp[it * 128 + 0];
        float4 p1 = cp[it * 128 + 64];
#pragma unroll
        for (int qi = 0; qi < Q; ++qi) {
            float d0 = fmaf(p0.x, nqx[qi], fmaf(p0.y, nqy[qi], fmaf(p0.z, nqz[qi], p0.w)));
            float k0 = mkkey(d0, ib);
            m3[qi] = __builtin_amdgcn_fmed3f(k0, m2[qi], m3[qi]);
            m2[qi] = __builtin_amdgcn_fmed3f(k0, m1[qi], m2[qi]);
            m1[qi] = fminf(k0, m1[qi]);
            float d1 = fmaf(p1.x, nqx[qi], fmaf(p1.y, nqy[qi], fmaf(p1.z, nqz[qi], p1.w)));
            float k1 = mkkey(d1, ib + 64u);
            m3[qi] = __builtin_amdgcn_fmed3f(k1, m2[qi], m3[qi]);
            m2[qi] = __builtin_amdgcn_fmed3f(k1, m1[qi], m2[qi]);
            m1[qi] = fminf(k1, m1[qi]);
        }
        ib += 128u;
    }
}

// ---- kernel 0: pack point sets as float4 (xyz,|p|^2), zero accumulators ----
__global__ void prep_kernel(const float* __restrict__ flow, const float* __restrict__ gt,
                            const float* __restrict__ coords,
                            float4* __restrict__ p1q, float4* __restrict__ p2q,
                            float4* __restrict__ wq, float* __restrict__ accs,
                            int* __restrict__ done) {
    int i = blockIdx.x * blockDim.x + threadIdx.x;
    if (i < N_PTS) {
        float cx = coords[3 * i + 0], cy = coords[3 * i + 1], cz = coords[3 * i + 2];
        float p2x = cx + gt[3 * i + 0], p2y = cy + gt[3 * i + 1], p2z = cz + gt[3 * i + 2];
        float wx = cx + flow[3 * i + 0], wy = cy + flow[3 * i + 1], wz = cz + flow[3 * i + 2];
        p1q[i] = make_float4(cx, cy, cz, cx * cx + cy * cy + cz * cz);
        p2q[i] = make_float4(p2x, p2y, p2z, p2x * p2x + p2y * p2y + p2z * p2z);
        wq[i]  = make_float4(wx, wy, wz, wx * wx + wy * wy + wz * wz);
    }
    if (i < 8) accs[i] = 0.0f;
    if (i == 8) done[0] = 0;
}

// ---- fused kernel: duration-balanced roles, contiguous mapping ----
__global__ __launch_bounds__(256) void fused4_kernel(const float4* __restrict__ p1q,
                                                     const float4* __restrict__ p2q,
                                                     const float4* __restrict__ wq,
                                                     const float* __restrict__ flow,
                                                     const int* __restrict__ ksm_p,
                                                     float* __restrict__ curv2,
                                                     float* __restrict__ mcurv,
                                                     float* __restrict__ crossk,
                                                     float* __restrict__ accs) {
    const int tid = threadIdx.x, lane = tid & 63, wv = tid >> 6;
    const int b = blockIdx.x;

    if (b >= R3_END) {
        // ---- reverse chamfer, QPW_REV queries per wave ----
        __shared__ float pmn[WPB];
        const int q0 = (b - R3_END) * (QPW_REV * WPB) + wv * QPW_REV;
        float nqx[QPW_REV], nqy[QPW_REV], nqz[QPW_REV], qw[QPW_REV], mn[QPW_REV];
#pragma unroll
        for (int qi = 0; qi < QPW_REV; ++qi) {
            float4 t = p2q[q0 + qi];
            nqx[qi] = -2.f * t.x; nqy[qi] = -2.f * t.y; nqz[qi] = -2.f * t.z;
            qw[qi] = t.w; mn[qi] = BIGF;
        }
        const float4* cp = wq + lane;
#pragma unroll 2
        for (int it = 0; it < N_PTS / 128; ++it) {
            float4 p0 = cp[it * 128 + 0];
            float4 p1 = cp[it * 128 + 64];
#pragma unroll
            for (int qi = 0; qi < QPW_REV; ++qi) {
                float d0 = fmaf(p0.x, nqx[qi], fmaf(p0.y, nqy[qi], fmaf(p0.z, nqz[qi], p0.w)));
                float d1 = fmaf(p1.x, nqx[qi], fmaf(p1.y, nqy[qi], fmaf(p1.z, nqz[qi], p1.w)));
                mn[qi] = fminf(mn[qi], fminf(d0, d1));
            }
        }
        float s = 0.f;
#pragma unroll
        for (int qi = 0; qi < QPW_REV; ++qi) {
            float v = mn[qi];
#pragma unroll
            for (int off = 1; off < 64; off <<= 1) v = fminf(v, __shfl_xor(v, off));
            s += v + qw[qi];  // unshift
        }
        if (lane == 0) pmn[wv] = s;
        __syncthreads();
        if (tid == 0) atomicAdd(&accs[1], pmn[0] + pmn[1] + pmn[2] + pmn[3]);
        return;
    }

    const int role = (b < R0_END) ? 0 : (b < R1_END) ? 1 : 3;
    const int blk = b - ((role == 0) ? 0 : (role == 1) ? R0_END : R1_END);
    const int q0 = blk * QPB + wv * QPW;

    const float4* qsrc = (role == 0) ? p2q : (role == 1) ? p1q : wq;
    const float4* cand = (role == 1) ? p1q : p2q;
    float nqx[QPW], nqy[QPW], nqz[QPW];
#pragma unroll
    for (int qi = 0; qi < QPW; ++qi) {
        float4 t = qsrc[q0 + qi];
        nqx[qi] = -2.f * t.x; nqy[qi] = -2.f * t.y; nqz[qi] = -2.f * t.z;
    }
    float m1[QPW], m2[QPW], m3[QPW];
    scank<QPW>(cand, nqx, nqy, nqz, m1, m2, m3, lane);

    if (role == 3) {
        // ---- cross: K=5, store set keys (unordered) via mbcnt scatter ----
        constexpr int K = 5;
#pragma unroll
        for (int qi = 0; qi < QPW; ++qi) {
            float k1 = m1[qi], k2 = m2[qi], k3 = m3[qi]; bool q1, q2, q3; float km;
            select_set<K>(p2q, nqx[qi], nqy[qi], nqz[qi], k1, k2, k3, q1, q2, q3, km, lane);
            const int q = q0 + qi;
            unsigned long long b1 = __ballot(q1), b2 = __ballot(q2), b3 = __ballot(q3);
            int c1 = __popcll(b1), c2 = __popcll(b2);
            if (q1) crossk[prefcnt(b1) * N_PTS + q] = k1;
            if (q2) crossk[(c1 + prefcnt(b2)) * N_PTS + q] = k2;
            if (q3) crossk[(c1 + c2 + prefcnt(b3)) * N_PTS + q] = k3;
        }
        return;
    }

    constexpr int K = 10;
    if (role == 0) {
        // ---- curvature of pc2: set-sum of neighbor positions ----
#pragma unroll
        for (int qi = 0; qi < QPW; ++qi) {
            float k1 = m1[qi], k2 = m2[qi], k3 = m3[qi]; bool q1, q2, q3; float km;
            select_set<K>(p2q, nqx[qi], nqy[qi], nqz[qi], k1, k2, k3, q1, q2, q3, km, lane);
            float ax = 0.f, ay = 0.f, az = 0.f;
            if (q1) { float4 nb = p2q[keyidx(k1)]; ax += nb.x; ay += nb.y; az += nb.z; }
            if (q2) { float4 nb = p2q[keyidx(k2)]; ax += nb.x; ay += nb.y; az += nb.z; }
            if (q3) { float4 nb = p2q[keyidx(k3)]; ax += nb.x; ay += nb.y; az += nb.z; }
            wave_add3(ax, ay, az);
            if (lane == 0) {
                const int q = q0 + qi;
                float4 t = p2q[q];
                curv2[q * 3 + 0] = (ax - 10.f * t.x) * (1.f / 9.f);
                curv2[q * 3 + 1] = (ay - 10.f * t.y) * (1.f / 9.f);
                curv2[q * 3 + 2] = (az - 10.f * t.z) * (1.f / 9.f);
            }
        }
    } else {
        // ---- pc1 self-kNN set -> moved_curv + smoothness (exclude max member) ----
        __shared__ float psm[WPB];
        const bool iall = (ksm_p[0] >= 10);   // ksm = 9 in practice: exclude km
        float smsum = 0.f;
#pragma unroll
        for (int qi = 0; qi < QPW; ++qi) {
            float k1 = m1[qi], k2 = m2[qi], k3 = m3[qi]; bool q1, q2, q3; float km;
            select_set<K>(p1q, nqx[qi], nqy[qi], nqz[qi], k1, k2, k3, q1, q2, q3, km, lane);
            const int q = q0 + qi;
            const float fqx = flow[q * 3 + 0], fqy = flow[q * 3 + 1], fqz = flow[q * 3 + 2];
            float ax = 0.f, ay = 0.f, az = 0.f, sm = 0.f;
            if (q1) {
                const int ni = keyidx(k1);
                float4 nb = wq[ni];
                ax += nb.x; ay += nb.y; az += nb.z;
                if (iall || k1 < km) {
                    float dx = flow[ni * 3 + 0] - fqx, dy = flow[ni * 3 + 1] - fqy, dz = flow[ni * 3 + 2] - fqz;
                    float sq = dx * dx + dy * dy + dz * dz;
                    sm += (sq == 0.f) ? 0.f : sqrtf(sq);
                }
            }
            if (q2) {
                const int ni = keyidx(k2);
                float4 nb = wq[ni];
                ax += nb.x; ay += nb.y; az += nb.z;
                if (iall || k2 < km) {
                    float dx = flow[ni * 3 + 0] - fqx, dy = flow[ni * 3 + 1] - fqy, dz = flow[ni * 3 + 2] - fqz;
                    float sq = dx * dx + dy * dy + dz * dz;
                    sm += (sq == 0.f) ? 0.f : sqrtf(sq);
                }
            }
            if (q3) {
                const int ni = keyidx(k3);
                float4 nb = wq[ni];
                ax += nb.x; ay += nb.y; az += nb.z;
                if (iall || k3 < km) {
                    float dx = flow[ni * 3 + 0] - fqx, dy = flow[ni * 3 + 1] - fqy, dz = flow[ni * 3 + 2] - fqz;
                    float sq = dx * dx + dy * dy + dz * dz;
                    sm += (sq == 0.f) ? 0.f : sqrtf(sq);
                }
            }
            wave_add4(ax, ay, az, sm);
            smsum += sm * 0.125f;  // /8.0 hard-coded in reference
            if (lane == 0) {
                float4 wqp = wq[q];
                mcurv[q * 3 + 0] = (ax - 10.f * wqp.x) * (1.f / 9.f);
                mcurv[q * 3 + 1] = (ay - 10.f * wqp.y) * (1.f / 9.f);
                mcurv[q * 3 + 2] = (az - 10.f * wqp.z) * (1.f / 9.f);
            }
        }
        if (lane == 0) psm[wv] = smsum;
        __syncthreads();
        if (tid == 0) atomicAdd(&accs[2], psm[0] + psm[1] + psm[2] + psm[3]);
    }
}

// ---- epilogue: exact-dist IDW + chamfer1/curv sums; last block finalizes ----
__global__ __launch_bounds__(256) void epi_kernel(const float* __restrict__ crossk,
                                                  const float4* __restrict__ wq,
                                                  const float4* __restrict__ p2q,
                                                  const float* __restrict__ curv2,
                                                  const float* __restrict__ mcurv,
                                                  float* __restrict__ accs,
                                                  int* __restrict__ done,
                                                  float* __restrict__ out) {
    __shared__ float pd1[WPB], pcv[WPB];
    const int tid = threadIdx.x, lane = tid & 63, wv = tid >> 6;
    const int q = blockIdx.x * 256 + tid;
    constexpr int K = 5;
    float4 qp = wq[q];
    float bd[K]; int bi[K];
#pragma unroll
    for (int r = 0; r < K; ++r) {
        bi[r] = keyidx(crossk[r * N_PTS + q]);
        float4 nb = p2q[bi[r]];
        float dx = qp.x - nb.x, dy = qp.y - nb.y, dz = qp.z - nb.z;
        bd[r] = dx * dx + dy * dy + dz * dz;   // exact squared distance
    }
    float w[K], wsum = 0.f;
#pragma unroll
    for (int r = 0; r < K; ++r) { w[r] = 1.f / (bd[r] + 1e-8f); wsum += w[r]; }
    float ix = 0.f, iy = 0.f, iz = 0.f;
#pragma unroll
    for (int r = 0; r < K; ++r) {
        float ww = w[r] / wsum;
        ix += ww * curv2[bi[r] * 3 + 0];
        iy += ww * curv2[bi[r] * 3 + 1];
        iz += ww * curv2[bi[r] * 3 + 2];
    }
    float dx = ix - mcurv[q * 3 + 0];
    float dy = iy - mcurv[q * 3 + 1];
    float dz = iz - mcurv[q * 3 + 2];
    float d1 = fminf(fminf(fminf(bd[0], bd[1]), fminf(bd[2], bd[3])), bd[4]);  // unordered set
    float cv = dx * dx + dy * dy + dz * dz;
#pragma unroll
    for (int off = 1; off < 64; off <<= 1) {
        d1 += __shfl_xor(d1, off);
        cv += __shfl_xor(cv, off);
    }
    if (lane == 0) { pd1[wv] = d1; pcv[wv] = cv; }
    __syncthreads();
    if (tid == 0) {
        atomicAdd(&accs[0], pd1[0] + pd1[1] + pd1[2] + pd1[3]);
        atomicAdd(&accs[3], pcv[0] + pcv[1] + pcv[2] + pcv[3]);
        __threadfence();
        int v = atomicAdd(done, 1);
        if (v == (int)gridDim.x - 1) {
            out[0] = W_CHAM * (accs[0] + accs[1]) + W_CURV * accs[3] + W_SMOO * accs[2];
        }
    }
}

extern "C" void kernel_launch(void* const* d_in, const int* in_sizes, int n_in,
                              void* d_out, int out_size, void* d_ws, size_t ws_size,
                              hipStream_t stream) {
    const float* flow   = (const float*)d_in[0];  // registration_pred (1,N,3)
    const float* gt     = (const float*)d_in[1];  // registration_gt   (1,N,3)
    const float* coords = (const float*)d_in[2];  // (N,3)
    const int*   ksm    = (const int*)d_in[3];    // smoothness_k (=9)

    float4* p1q   = (float4*)d_ws;           // N float4 (xyz,|p|^2)
    float4* p2q   = p1q + N_PTS;
    float4* wq    = p2q + N_PTS;
    float*  curv2 = (float*)(wq + N_PTS);    // 3N
    float*  mcurv = curv2 + 3 * N_PTS;       // 3N
    float*  crossk = mcurv + 3 * N_PTS;      // 5N keys
    float*  accs  = crossk + 5 * N_PTS;      // 8
    int*    done  = (int*)(accs + 8);        // 1
    float*  out   = (float*)d_out;

    prep_kernel<<<(N_PTS + 255) / 256, 256, 0, stream>>>(flow, gt, coords, p1q, p2q, wq,
                                                         accs, done);
    fused4_kernel<<<GRID_TOTAL, 256, 0, stream>>>(p1q, p2q, wq, flow, ksm,
                                                  curv2, mcurv, crossk, accs);
    epi_kernel<<<N_PTS / 256, 256, 0, stream>>>(crossk, wq, p2q, curv2, mcurv,
                                                accs, done, out);
}

// Round 19
// 143.445 us; speedup vs baseline: 1.1902x; 1.1902x over previous
//
#include <hip/hip_runtime.h>
#include <hip/hip_bf16.h>
#include <math.h>

#define N_PTS 8192
#define QPW 4                 // queries per wave (top-K roles)
#define QPW_REV 8             // queries per wave (reverse chamfer role)
#define WPB 4                 // waves per block
#define QPB (QPW * WPB)       // 16 queries per block (top-K roles)
#define BLKS_TOPK (N_PTS / QPB)        // 512 blocks per top-K role
#define BLKS_REV  (N_PTS / (QPW_REV * WPB))  // 256 blocks for rev

#define R0_END BLKS_TOPK                  // 512   curv2 scan
#define R1_END (2 * BLKS_TOPK)            // 1024  pc1 scan
#define R3_END (3 * BLKS_TOPK)            // 1536  cross scan
#define GRID_TOTAL (3 * BLKS_TOPK + BLKS_REV)  // 1792

// F_CHAMFER*ALPHA0 = 0.02, F_CURVATURE*ALPHA0 = 0.006, F_SMOOTH*ALPHA0 = 0.01
#define W_CHAM 0.02f
#define W_CURV 0.006f
#define W_SMOO 0.01f

#define BIGF 1e30f
#define IDX_MASK 0x1FFFu
#define KEY_MASK 0xFFFFE000u

__device__ __forceinline__ float mkkey(float d, unsigned idx) {
    return __uint_as_float((__float_as_uint(d) & KEY_MASK) | idx);
}
__device__ __forceinline__ int keyidx(float k) {
    return (int)(__float_as_uint(k) & IDX_MASK);
}
// monotonic float-bits -> unsigned map (order-preserving)
__device__ __forceinline__ unsigned monou(float k) {
    int b = __float_as_int(k);
    return (unsigned)(b ^ ((b >> 31) | 0x80000000));
}
// prefix popcount of mask below this lane
__device__ __forceinline__ int prefcnt(unsigned long long m) {
    return __builtin_amdgcn_mbcnt_hi((unsigned)(m >> 32),
           __builtin_amdgcn_mbcnt_lo((unsigned)m, 0));
}

// ---- value-only sorted insert (fallback path only; proven) ----
template <int K>
__device__ __forceinline__ void kinsert(float kv, float (&bd)[K]) {
    bd[K - 1] = kv;
#pragma unroll
    for (int s = K - 1; s > 0; --s) {
        float lo = fminf(bd[s - 1], bd[s]);
        float hi = fmaxf(bd[s - 1], bd[s]);
        bd[s - 1] = lo; bd[s] = hi;
    }
}

// ---- proven sorted merge (cold failsafe only) ----
template <int K>
__device__ void merge_keys(float m1, float m2, float m3, float (&bd)[K], int lane) {
    float h0 = m1, h1 = m2, h2 = m3;
#pragma unroll
    for (int r = 0; r < K; ++r) {
        float bv = h0;
#pragma unroll
        for (int off = 1; off < 64; off <<= 1) bv = fminf(bv, __shfl_xor(bv, off));
        bd[r] = bv;
        if (h0 == bv) { h0 = h1; h1 = h2; h2 = BIGF; }
    }
}

// ---- exact fixed-tau FULL rescan in key space (proven) ----
template <int K>
__device__ void tau_rescan(const float4* __restrict__ cand,
                           float nqx, float nqy, float nqz, float tau,
                           float (&bd)[K], int lane) {
#pragma unroll
    for (int r = 0; r < K; ++r) bd[r] = BIGF;
    const float4* cp = cand + lane;
    unsigned ib = (unsigned)lane;
    for (int it = 0; it < N_PTS / 64; ++it) {
        float4 p = cp[it * 64];
        float d = fmaf(p.x, nqx, fmaf(p.y, nqy, fmaf(p.z, nqz, p.w)));
        float kc = mkkey(d, ib);
        unsigned long long m = __ballot(kc <= tau);
        while (m) {
            int b = __builtin_ctzll(m);
            m &= m - 1;
            float kv = __shfl(kc, b);
            if (kv < bd[K - 1]) kinsert<K>(kv, bd);
        }
        ib += 64;
    }
}

// ---- rank-pivot set selection: top-K as SET (k1..k3/q1..q3 slots) + km = max member ----
template <int K>
__device__ void select_set(const float4* __restrict__ cand,
                           float nqx, float nqy, float nqz,
                           float& k1, float& k2, float& k3,
                           bool& q1, bool& q2, bool& q3, float& km, int lane) {
    const unsigned u1 = monou(k1), u2 = monou(k2), u3 = monou(k3);
    unsigned lo = 0u, hi = 0xFFFFFFFFu, piv = 0u;
    int cnt = -1;
    unsigned long long b3 = 0ull;
    for (int it = 0; it < 34; ++it) {
        piv = lo + ((hi - lo) >> 1);
        unsigned long long b1 = __ballot(u1 <= piv);
        unsigned long long b2 = __ballot(u2 <= piv);
        b3 = __ballot(u3 <= piv);
        cnt = __popcll(b1) + __popcll(b2) + __popcll(b3);
        if (cnt == K) break;
        if (cnt < K) lo = piv + 1; else hi = piv - 1;
    }
    bool setok = (cnt == K);
    bool fail;
    float bdK[K];
    if (setok) {
        q1 = (u1 <= piv); q2 = (u2 <= piv); q3 = (u3 <= piv);
        float t = q3 ? k3 : (q2 ? k2 : (q1 ? k1 : -BIGF));
#pragma unroll
        for (int off = 1; off < 64; off <<= 1) t = fmaxf(t, __shfl_xor(t, off));
        km = t;
        fail = (b3 != 0ull);   // some lane contributed its 3rd -> 4th may be hidden
    } else {
        merge_keys<K>(k1, k2, k3, bdK, lane);   // mathematically unreachable failsafe
        km = bdK[K - 1];
        fail = (__ballot(k3 <= km) != 0ull);
    }
    if (fail) { tau_rescan<K>(cand, nqx, nqy, nqz, km, bdK, lane); setok = false; }
    if (!setok) {
        float kv = BIGF;
#pragma unroll
        for (int r = 0; r < K; ++r) if (lane == r) kv = bdK[r];
        k1 = kv; k2 = BIGF; k3 = BIGF;
        q1 = (lane < K); q2 = false; q3 = false;
        km = bdK[K - 1];
    }
}

__device__ __forceinline__ void wave_add3(float& a, float& b, float& c) {
#pragma unroll
    for (int off = 1; off < 64; off <<= 1) {
        a += __shfl_xor(a, off);
        b += __shfl_xor(b, off);
        c += __shfl_xor(c, off);
    }
}
__device__ __forceinline__ void wave_add4(float& a, float& b, float& c, float& d) {
#pragma unroll
    for (int off = 1; off < 64; off <<= 1) {
        a += __shfl_xor(a, off);
        b += __shfl_xor(b, off);
        c += __shfl_xor(c, off);
        d += __shfl_xor(d, off);
    }
}

// ---- branchless Q-query key scan, 4-candidate strips (proven R16/R17) ----
template <int Q>
__device__ __forceinline__ void scank(const float4* __restrict__ cand,
                                      const float (&nqx)[Q], const float (&nqy)[Q],
                                      const float (&nqz)[Q],
                                      float (&m1)[Q], float (&m2)[Q], float (&m3)[Q],
                                      int lane) {
#pragma unroll
    for (int qi = 0; qi < Q; ++qi) { m1[qi] = BIGF; m2[qi] = BIGF; m3[qi] = BIGF; }
    const float4* cp = cand + lane;
    unsigned ib = (unsigned)lane;
#pragma unroll 2
    for (int it = 0; it < N_PTS / 256; ++it) {
        float4 p0 = cp[it * 256 + 0];
        float4 p1 = cp[it * 256 + 64];
        float4 p2 = cp[it * 256 + 128];
        float4 p3 = cp[it * 256 + 192];
#pragma unroll
        for (int qi = 0; qi < Q; ++qi) {
            float d0 = fmaf(p0.x, nqx[qi], fmaf(p0.y, nqy[qi], fmaf(p0.z, nqz[qi], p0.w)));
            float k0 = mkkey(d0, ib);
            m3[qi] = __builtin_amdgcn_fmed3f(k0, m2[qi], m3[qi]);
            m2[qi] = __builtin_amdgcn_fmed3f(k0, m1[qi], m2[qi]);
            m1[qi] = fminf(k0, m1[qi]);
            float d1 = fmaf(p1.x, nqx[qi], fmaf(p1.y, nqy[qi], fmaf(p1.z, nqz[qi], p1.w)));
            float k1 = mkkey(d1, ib + 64u);
            m3[qi] = __builtin_amdgcn_fmed3f(k1, m2[qi], m3[qi]);
            m2[qi] = __builtin_amdgcn_fmed3f(k1, m1[qi], m2[qi]);
            m1[qi] = fminf(k1, m1[qi]);
            float d2 = fmaf(p2.x, nqx[qi], fmaf(p2.y, nqy[qi], fmaf(p2.z, nqz[qi], p2.w)));
            float k2 = mkkey(d2, ib + 128u);
            m3[qi] = __builtin_amdgcn_fmed3f(k2, m2[qi], m3[qi]);
            m2[qi] = __builtin_amdgcn_fmed3f(k2, m1[qi], m2[qi]);
            m1[qi] = fminf(k2, m1[qi]);
            float d3 = fmaf(p3.x, nqx[qi], fmaf(p3.y, nqy[qi], fmaf(p3.z, nqz[qi], p3.w)));
            float k3 = mkkey(d3, ib + 192u);
            m3[qi] = __builtin_amdgcn_fmed3f(k3, m2[qi], m3[qi]);
            m2[qi] = __builtin_amdgcn_fmed3f(k3, m1[qi], m2[qi]);
            m1[qi] = fminf(k3, m1[qi]);
        }
        ib += 256u;
    }
}

// ---- kernel 0: pack point sets as float4 (xyz,|p|^2), zero accumulators ----
__global__ void prep_kernel(const float* __restrict__ flow, const float* __restrict__ gt,
                            const float* __restrict__ coords,
                            float4* __restrict__ p1q, float4* __restrict__ p2q,
                            float4* __restrict__ wq, float* __restrict__ accs,
                            int* __restrict__ done) {
    int i = blockIdx.x * blockDim.x + threadIdx.x;
    if (i < N_PTS) {
        float cx = coords[3 * i + 0], cy = coords[3 * i + 1], cz = coords[3 * i + 2];
        float p2x = cx + gt[3 * i + 0], p2y = cy + gt[3 * i + 1], p2z = cz + gt[3 * i + 2];
        float wx = cx + flow[3 * i + 0], wy = cy + flow[3 * i + 1], wz = cz + flow[3 * i + 2];
        p1q[i] = make_float4(cx, cy, cz, cx * cx + cy * cy + cz * cz);
        p2q[i] = make_float4(p2x, p2y, p2z, p2x * p2x + p2y * p2y + p2z * p2z);
        wq[i]  = make_float4(wx, wy, wz, wx * wx + wy * wy + wz * wz);
    }
    if (i < 8) accs[i] = 0.0f;
    if (i == 8) done[0] = 0;
}

// ---- fused kernel: duration-balanced roles, contiguous mapping ----
__global__ __launch_bounds__(256) void fused4_kernel(const float4* __restrict__ p1q,
                                                     const float4* __restrict__ p2q,
                                                     const float4* __restrict__ wq,
                                                     const float* __restrict__ flow,
                                                     const int* __restrict__ ksm_p,
                                                     float* __restrict__ curv2,
                                                     float* __restrict__ mcurv,
                                                     float* __restrict__ crossk,
                                                     float* __restrict__ accs) {
    const int tid = threadIdx.x, lane = tid & 63, wv = tid >> 6;
    const int b = blockIdx.x;

    if (b >= R3_END) {
        // ---- reverse chamfer, QPW_REV queries per wave ----
        __shared__ float pmn[WPB];
        const int q0 = (b - R3_END) * (QPW_REV * WPB) + wv * QPW_REV;
        float nqx[QPW_REV], nqy[QPW_REV], nqz[QPW_REV], qw[QPW_REV], mn[QPW_REV];
#pragma unroll
        for (int qi = 0; qi < QPW_REV; ++qi) {
            float4 t = p2q[q0 + qi];
            nqx[qi] = -2.f * t.x; nqy[qi] = -2.f * t.y; nqz[qi] = -2.f * t.z;
            qw[qi] = t.w; mn[qi] = BIGF;
        }
        const float4* cp = wq + lane;
#pragma unroll 2
        for (int it = 0; it < N_PTS / 128; ++it) {
            float4 p0 = cp[it * 128 + 0];
            float4 p1 = cp[it * 128 + 64];
#pragma unroll
            for (int qi = 0; qi < QPW_REV; ++qi) {
                float d0 = fmaf(p0.x, nqx[qi], fmaf(p0.y, nqy[qi], fmaf(p0.z, nqz[qi], p0.w)));
                float d1 = fmaf(p1.x, nqx[qi], fmaf(p1.y, nqy[qi], fmaf(p1.z, nqz[qi], p1.w)));
                mn[qi] = fminf(mn[qi], fminf(d0, d1));
            }
        }
        float s = 0.f;
#pragma unroll
        for (int qi = 0; qi < QPW_REV; ++qi) {
            float v = mn[qi];
#pragma unroll
            for (int off = 1; off < 64; off <<= 1) v = fminf(v, __shfl_xor(v, off));
            s += v + qw[qi];  // unshift
        }
        if (lane == 0) pmn[wv] = s;
        __syncthreads();
        if (tid == 0) atomicAdd(&accs[1], pmn[0] + pmn[1] + pmn[2] + pmn[3]);
        return;
    }

    const int role = (b < R0_END) ? 0 : (b < R1_END) ? 1 : 3;
    const int blk = b - ((role == 0) ? 0 : (role == 1) ? R0_END : R1_END);
    const int q0 = blk * QPB + wv * QPW;

    const float4* qsrc = (role == 0) ? p2q : (role == 1) ? p1q : wq;
    const float4* cand = (role == 1) ? p1q : p2q;
    float nqx[QPW], nqy[QPW], nqz[QPW];
#pragma unroll
    for (int qi = 0; qi < QPW; ++qi) {
        float4 t = qsrc[q0 + qi];
        nqx[qi] = -2.f * t.x; nqy[qi] = -2.f * t.y; nqz[qi] = -2.f * t.z;
    }
    float m1[QPW], m2[QPW], m3[QPW];
    scank<QPW>(cand, nqx, nqy, nqz, m1, m2, m3, lane);

    if (role == 3) {
        // ---- cross: K=5, store set keys (unordered) via mbcnt scatter ----
        constexpr int K = 5;
#pragma unroll
        for (int qi = 0; qi < QPW; ++qi) {
            float k1 = m1[qi], k2 = m2[qi], k3 = m3[qi]; bool q1, q2, q3; float km;
            select_set<K>(p2q, nqx[qi], nqy[qi], nqz[qi], k1, k2, k3, q1, q2, q3, km, lane);
            const int q = q0 + qi;
            unsigned long long b1 = __ballot(q1), b2 = __ballot(q2), b3 = __ballot(q3);
            int c1 = __popcll(b1), c2 = __popcll(b2);
            if (q1) crossk[prefcnt(b1) * N_PTS + q] = k1;
            if (q2) crossk[(c1 + prefcnt(b2)) * N_PTS + q] = k2;
            if (q3) crossk[(c1 + c2 + prefcnt(b3)) * N_PTS + q] = k3;
        }
        return;
    }

    constexpr int K = 10;
    if (role == 0) {
        // ---- curvature of pc2: set-sum of neighbor positions ----
#pragma unroll
        for (int qi = 0; qi < QPW; ++qi) {
            float k1 = m1[qi], k2 = m2[qi], k3 = m3[qi]; bool q1, q2, q3; float km;
            select_set<K>(p2q, nqx[qi], nqy[qi], nqz[qi], k1, k2, k3, q1, q2, q3, km, lane);
            float ax = 0.f, ay = 0.f, az = 0.f;
            if (q1) { float4 nb = p2q[keyidx(k1)]; ax += nb.x; ay += nb.y; az += nb.z; }
            if (q2) { float4 nb = p2q[keyidx(k2)]; ax += nb.x; ay += nb.y; az += nb.z; }
            if (q3) { float4 nb = p2q[keyidx(k3)]; ax += nb.x; ay += nb.y; az += nb.z; }
            wave_add3(ax, ay, az);
            if (lane == 0) {
                const int q = q0 + qi;
                float4 t = p2q[q];
                curv2[q * 3 + 0] = (ax - 10.f * t.x) * (1.f / 9.f);
                curv2[q * 3 + 1] = (ay - 10.f * t.y) * (1.f / 9.f);
                curv2[q * 3 + 2] = (az - 10.f * t.z) * (1.f / 9.f);
            }
        }
    } else {
        // ---- pc1 self-kNN set -> moved_curv + smoothness (exclude max member) ----
        __shared__ float psm[WPB];
        const bool iall = (ksm_p[0] >= 10);   // ksm = 9 in practice: exclude km
        float smsum = 0.f;
#pragma unroll
        for (int qi = 0; qi < QPW; ++qi) {
            float k1 = m1[qi], k2 = m2[qi], k3 = m3[qi]; bool q1, q2, q3; float km;
            select_set<K>(p1q, nqx[qi], nqy[qi], nqz[qi], k1, k2, k3, q1, q2, q3, km, lane);
            const int q = q0 + qi;
            const float fqx = flow[q * 3 + 0], fqy = flow[q * 3 + 1], fqz = flow[q * 3 + 2];
            float ax = 0.f, ay = 0.f, az = 0.f, sm = 0.f;
            if (q1) {
                const int ni = keyidx(k1);
                float4 nb = wq[ni];
                ax += nb.x; ay += nb.y; az += nb.z;
                if (iall || k1 < km) {
                    float dx = flow[ni * 3 + 0] - fqx, dy = flow[ni * 3 + 1] - fqy, dz = flow[ni * 3 + 2] - fqz;
                    float sq = dx * dx + dy * dy + dz * dz;
                    sm += (sq == 0.f) ? 0.f : sqrtf(sq);
                }
            }
            if (q2) {
                const int ni = keyidx(k2);
                float4 nb = wq[ni];
                ax += nb.x; ay += nb.y; az += nb.z;
                if (iall || k2 < km) {
                    float dx = flow[ni * 3 + 0] - fqx, dy = flow[ni * 3 + 1] - fqy, dz = flow[ni * 3 + 2] - fqz;
                    float sq = dx * dx + dy * dy + dz * dz;
                    sm += (sq == 0.f) ? 0.f : sqrtf(sq);
                }
            }
            if (q3) {
                const int ni = keyidx(k3);
                float4 nb = wq[ni];
                ax += nb.x; ay += nb.y; az += nb.z;
                if (iall || k3 < km) {
                    float dx = flow[ni * 3 + 0] - fqx, dy = flow[ni * 3 + 1] - fqy, dz = flow[ni * 3 + 2] - fqz;
                    float sq = dx * dx + dy * dy + dz * dz;
                    sm += (sq == 0.f) ? 0.f : sqrtf(sq);
                }
            }
            wave_add4(ax, ay, az, sm);
            smsum += sm * 0.125f;  // /8.0 hard-coded in reference
            if (lane == 0) {
                float4 wqp = wq[q];
                mcurv[q * 3 + 0] = (ax - 10.f * wqp.x) * (1.f / 9.f);
                mcurv[q * 3 + 1] = (ay - 10.f * wqp.y) * (1.f / 9.f);
                mcurv[q * 3 + 2] = (az - 10.f * wqp.z) * (1.f / 9.f);
            }
        }
        if (lane == 0) psm[wv] = smsum;
        __syncthreads();
        if (tid == 0) atomicAdd(&accs[2], psm[0] + psm[1] + psm[2] + psm[3]);
    }
}

// ---- epilogue: exact-dist IDW + chamfer1/curv sums; last block finalizes ----
__global__ __launch_bounds__(256) void epi_kernel(const float* __restrict__ crossk,
                                                  const float4* __restrict__ wq,
                                                  const float4* __restrict__ p2q,
                                                  const float* __restrict__ curv2,
                                                  const float* __restrict__ mcurv,
                                                  float* __restrict__ accs,
                                                  int* __restrict__ done,
                                                  float* __restrict__ out) {
    __shared__ float pd1[WPB], pcv[WPB];
    const int tid = threadIdx.x, lane = tid & 63, wv = tid >> 6;
    const int q = blockIdx.x * 256 + tid;
    constexpr int K = 5;
    float4 qp = wq[q];
    float bd[K]; int bi[K];
#pragma unroll
    for (int r = 0; r < K; ++r) {
        bi[r] = keyidx(crossk[r * N_PTS + q]);
        float4 nb = p2q[bi[r]];
        float dx = qp.x - nb.x, dy = qp.y - nb.y, dz = qp.z - nb.z;
        bd[r] = dx * dx + dy * dy + dz * dz;   // exact squared distance
    }
    float w[K], wsum = 0.f;
#pragma unroll
    for (int r = 0; r < K; ++r) { w[r] = 1.f / (bd[r] + 1e-8f); wsum += w[r]; }
    float ix = 0.f, iy = 0.f, iz = 0.f;
#pragma unroll
    for (int r = 0; r < K; ++r) {
        float ww = w[r] / wsum;
        ix += ww * curv2[bi[r] * 3 + 0];
        iy += ww * curv2[bi[r] * 3 + 1];
        iz += ww * curv2[bi[r] * 3 + 2];
    }
    float dx = ix - mcurv[q * 3 + 0];
    float dy = iy - mcurv[q * 3 + 1];
    float dz = iz - mcurv[q * 3 + 2];
    float d1 = fminf(fminf(fminf(bd[0], bd[1]), fminf(bd[2], bd[3])), bd[4]);  // unordered set
    float cv = dx * dx + dy * dy + dz * dz;
#pragma unroll
    for (int off = 1; off < 64; off <<= 1) {
        d1 += __shfl_xor(d1, off);
        cv += __shfl_xor(cv, off);
    }
    if (lane == 0) { pd1[wv] = d1; pcv[wv] = cv; }
    __syncthreads();
    if (tid == 0) {
        atomicAdd(&accs[0], pd1[0] + pd1[1] + pd1[2] + pd1[3]);
        atomicAdd(&accs[3], pcv[0] + pcv[1] + pcv[2] + pcv[3]);
        __threadfence();
        int v = atomicAdd(done, 1);
        if (v == (int)gridDim.x - 1) {
            out[0] = W_CHAM * (accs[0] + accs[1]) + W_CURV * accs[3] + W_SMOO * accs[2];
        }
    }
}

extern "C" void kernel_launch(void* const* d_in, const int* in_sizes, int n_in,
                              void* d_out, int out_size, void* d_ws, size_t ws_size,
                              hipStream_t stream) {
    const float* flow   = (const float*)d_in[0];  // registration_pred (1,N,3)
    const float* gt     = (const float*)d_in[1];  // registration_gt   (1,N,3)
    const float* coords = (const float*)d_in[2];  // (N,3)
    const int*   ksm    = (const int*)d_in[3];    // smoothness_k (=9)

    float4* p1q   = (float4*)d_ws;           // N float4 (xyz,|p|^2)
    float4* p2q   = p1q + N_PTS;
    float4* wq    = p2q + N_PTS;
    float*  curv2 = (float*)(wq + N_PTS);    // 3N
    float*  mcurv = curv2 + 3 * N_PTS;       // 3N
    float*  crossk = mcurv + 3 * N_PTS;      // 5N keys
    float*  accs  = crossk + 5 * N_PTS;      // 8
    int*    done  = (int*)(accs + 8);        // 1
    float*  out   = (float*)d_out;

    prep_kernel<<<(N_PTS + 255) / 256, 256, 0, stream>>>(flow, gt, coords, p1q, p2q, wq,
                                                         accs, done);
    fused4_kernel<<<GRID_TOTAL, 256, 0, stream>>>(p1q, p2q, wq, flow, ksm,
                                                  curv2, mcurv, crossk, accs);
    epi_kernel<<<N_PTS / 256, 256, 0, stream>>>(crossk, wq, p2q, curv2, mcurv,
                                                accs, done, out);
}